// Round 1
// baseline (247.258 us; speedup 1.0000x reference)
//
#include <hip/hip_runtime.h>
#include <hip/hip_bf16.h>

typedef __hip_bfloat16 bf16;
typedef __attribute__((ext_vector_type(8))) short short8;
typedef __attribute__((ext_vector_type(4))) float f32x4;

#define DDIM 1024
#define SEQ  4096
#define NB   4
#define MTOT (NB*SEQ)   // 16384 rows

static __device__ __forceinline__ unsigned short f2bf(float f) {
    __hip_bfloat16 h = __float2bfloat16(f);
    unsigned short u; __builtin_memcpy(&u, &h, 2); return u;
}

// ---------------------------------------------------------------- cast weights
__global__ __launch_bounds__(256) void cast_w_kernel(
    const float* __restrict__ w1, const float* __restrict__ w2,
    unsigned short* __restrict__ w1b, unsigned short* __restrict__ w2b)
{
    size_t idx = ((size_t)blockIdx.x*256 + threadIdx.x) * 4;   // grid 1024 -> 1M elems
    float4 a = *(const float4*)(w1 + idx);
    ushort4 o; o.x=f2bf(a.x); o.y=f2bf(a.y); o.z=f2bf(a.z); o.w=f2bf(a.w);
    *(ushort4*)(w1b + idx) = o;
    float4 b = *(const float4*)(w2 + idx);
    o.x=f2bf(b.x); o.y=f2bf(b.y); o.z=f2bf(b.z); o.w=f2bf(b.w);
    *(ushort4*)(w2b + idx) = o;
}

// ------------------------------------------------------- column sum of x (per batch)
__global__ __launch_bounds__(256) void colsum_partial_kernel(
    const float* __restrict__ x, float* __restrict__ partial)
{
    // grid (4, NB, 32)
    int d  = blockIdx.x*256 + threadIdx.x;
    int b  = blockIdx.y;
    int sl = blockIdx.z;
    const float* p = x + ((size_t)b*SEQ + (size_t)sl*128)*DDIM + d;
    float s = 0.f;
    #pragma unroll 4
    for (int i = 0; i < 128; ++i) s += p[(size_t)i*DDIM];
    partial[((size_t)sl*NB + b)*DDIM + d] = s;
}

__global__ __launch_bounds__(256) void colsum_reduce_kernel(
    const float* __restrict__ partial, float* __restrict__ xsum)
{
    // grid (4, NB)
    int d = blockIdx.x*256 + threadIdx.x;
    int b = blockIdx.y;
    float s = 0.f;
    #pragma unroll
    for (int sl = 0; sl < 32; ++sl) s += partial[((size_t)sl*NB + b)*DDIM + d];
    xsum[b*DDIM + d] = s;
}

// ------------------------------------------------------- small matvec: vout = vin @ W^T
__global__ __launch_bounds__(256) void matvec_kernel(
    const float* __restrict__ W, const float* __restrict__ vin, float* __restrict__ vout)
{
    // grid (64, NB): block computes 16 outputs; 16 threads per output
    int b = blockIdx.y;
    int g = threadIdx.x >> 4;
    int t = threadIdx.x & 15;
    int e = blockIdx.x*16 + g;
    const float* w = W + (size_t)e*DDIM;
    const float* v = vin + b*DDIM;
    float s = 0.f;
    for (int k = t; k < DDIM; k += 16) s += w[k]*v[k];
    #pragma unroll
    for (int o = 8; o; o >>= 1) s += __shfl_down(s, o, 16);
    if (t == 0) vout[b*DDIM + e] = s;
}

// ------------------------------------------------------- LN1: x1 = LN(x + attnvec)
__global__ __launch_bounds__(256) void ln1_kernel(
    const float* __restrict__ x, const float* __restrict__ avec,
    const float* __restrict__ g1, const float* __restrict__ b1,
    unsigned short* __restrict__ x1b, float* __restrict__ x1f)
{
    int row = blockIdx.x;
    int b   = row >> 12;          // row / SEQ
    int tid = threadIdx.x;
    const float4* xr = (const float4*)(x + (size_t)row*DDIM);
    const float4* av = (const float4*)(avec + (size_t)b*DDIM);
    float4 xv = xr[tid], a4 = av[tid];
    float y0 = xv.x+a4.x, y1 = xv.y+a4.y, y2 = xv.z+a4.z, y3 = xv.w+a4.w;
    float s  = y0+y1+y2+y3;
    float ss = y0*y0+y1*y1+y2*y2+y3*y3;
    #pragma unroll
    for (int o = 32; o; o >>= 1) { s += __shfl_down(s,o,64); ss += __shfl_down(ss,o,64); }
    __shared__ float red[8];
    if ((tid&63) == 0) { red[tid>>6] = s; red[4+(tid>>6)] = ss; }
    __syncthreads();
    float St = red[0]+red[1]+red[2]+red[3];
    float Sq = red[4]+red[5]+red[6]+red[7];
    float mu = St*(1.0f/DDIM);
    float rs = rsqrtf(Sq*(1.0f/DDIM) - mu*mu + 1e-5f);
    float4 g4 = ((const float4*)g1)[tid];
    float4 bb = ((const float4*)b1)[tid];
    float n0 = (y0-mu)*rs*g4.x + bb.x;
    float n1 = (y1-mu)*rs*g4.y + bb.y;
    float n2 = (y2-mu)*rs*g4.z + bb.z;
    float n3 = (y3-mu)*rs*g4.w + bb.w;
    ushort4 o; o.x=f2bf(n0); o.y=f2bf(n1); o.z=f2bf(n2); o.w=f2bf(n3);
    *(ushort4*)(x1b + (size_t)row*DDIM + tid*4) = o;
    float4 f; f.x=n0; f.y=n1; f.z=n2; f.w=n3;
    ((float4*)(x1f + (size_t)row*DDIM))[tid] = f;
}

// ------------------------------------------------------- bf16 MFMA GEMM  C = A @ W^T
// MODE 1: out = gelu(C + bias) -> bf16      MODE 2: outf += C + bias (residual in outf)
template<int MODE>
__global__ __launch_bounds__(256) void gemm_kernel(
    const bf16* __restrict__ A, const bf16* __restrict__ Bw,
    const float* __restrict__ bias,
    unsigned short* __restrict__ outb, float* __restrict__ outf,
    int K, int N)
{
    __shared__ bf16 As[128*32];
    __shared__ bf16 Bs[128*32];
    const int tid  = threadIdx.x;
    const int wave = tid >> 6, lane = tid & 63;
    const size_t bm = (size_t)blockIdx.x * 128;
    const size_t bn = (size_t)blockIdx.y * 128;
    f32x4 acc[4][4] = {};
    const int wr = (wave>>1)*64, wc = (wave&1)*64;
    const int srow = lane >> 2;         // row within 16-row chunk
    const int skof = (lane & 3) * 8;    // k offset of this lane's 16B
    const int frow = lane & 15;
    const int fk   = (lane >> 4) * 8;

    for (int kt = 0; kt < K; kt += 32) {
        #pragma unroll
        for (int c = 0; c < 2; ++c) {
            int chunk = c*4 + wave;     // wave-uniform
            const bf16* ga = A  + (bm + chunk*16 + srow)*(size_t)K + kt + skof;
            const bf16* gb = Bw + (bn + chunk*16 + srow)*(size_t)K + kt + skof;
            __builtin_amdgcn_global_load_lds(
                (const __attribute__((address_space(1))) void*)ga,
                (__attribute__((address_space(3))) void*)(As + chunk*512), 16, 0, 0);
            __builtin_amdgcn_global_load_lds(
                (const __attribute__((address_space(1))) void*)gb,
                (__attribute__((address_space(3))) void*)(Bs + chunk*512), 16, 0, 0);
        }
        __syncthreads();
        short8 af[4], bfr[4];
        #pragma unroll
        for (int m = 0; m < 4; ++m) af[m]  = *(const short8*)(As + (wr + m*16 + frow)*32 + fk);
        #pragma unroll
        for (int n = 0; n < 4; ++n) bfr[n] = *(const short8*)(Bs + (wc + n*16 + frow)*32 + fk);
        #pragma unroll
        for (int m = 0; m < 4; ++m)
            #pragma unroll
            for (int n = 0; n < 4; ++n)
                acc[m][n] = __builtin_amdgcn_mfma_f32_16x16x32_bf16(af[m], bfr[n], acc[m][n], 0, 0, 0);
        __syncthreads();
    }

    const int crow = (lane>>4)*4, ccol = lane & 15;
    #pragma unroll
    for (int m = 0; m < 4; ++m) {
        #pragma unroll
        for (int n = 0; n < 4; ++n) {
            size_t col = bn + wc + n*16 + ccol;
            float bv = bias[col];
            #pragma unroll
            for (int r = 0; r < 4; ++r) {
                size_t row = bm + wr + m*16 + crow + r;
                float v = acc[m][n][r] + bv;
                if (MODE == 1) {
                    float ge = 0.5f*v*(1.0f + erff(v*0.70710678118f));
                    outb[row*(size_t)N + col] = f2bf(ge);
                } else {
                    float* p = outf + row*(size_t)N + col;
                    *p = v + *p;           // residual x1 (fp32) already there
                }
            }
        }
    }
}

// ------------------------------------------------------- LN2 in-place on d_out
__global__ __launch_bounds__(256) void ln2_kernel(
    float* __restrict__ out, const float* __restrict__ g2, const float* __restrict__ b2)
{
    int row = blockIdx.x;
    int tid = threadIdx.x;
    float4* orow = (float4*)(out + (size_t)row*DDIM);
    float4 y = orow[tid];
    float s  = y.x+y.y+y.z+y.w;
    float ss = y.x*y.x+y.y*y.y+y.z*y.z+y.w*y.w;
    #pragma unroll
    for (int o = 32; o; o >>= 1) { s += __shfl_down(s,o,64); ss += __shfl_down(ss,o,64); }
    __shared__ float red[8];
    if ((tid&63) == 0) { red[tid>>6] = s; red[4+(tid>>6)] = ss; }
    __syncthreads();
    float St = red[0]+red[1]+red[2]+red[3];
    float Sq = red[4]+red[5]+red[6]+red[7];
    float mu = St*(1.0f/DDIM);
    float rs = rsqrtf(Sq*(1.0f/DDIM) - mu*mu + 1e-5f);
    float4 g4 = ((const float4*)g2)[tid];
    float4 bb = ((const float4*)b2)[tid];
    float4 n;
    n.x = (y.x-mu)*rs*g4.x + bb.x;
    n.y = (y.y-mu)*rs*g4.y + bb.y;
    n.z = (y.z-mu)*rs*g4.z + bb.z;
    n.w = (y.w-mu)*rs*g4.w + bb.w;
    orow[tid] = n;
}

// ---------------------------------------------------------------- launch
extern "C" void kernel_launch(void* const* d_in, const int* in_sizes, int n_in,
                              void* d_out, int out_size, void* d_ws, size_t ws_size,
                              hipStream_t stream)
{
    const float* x     = (const float*)d_in[0];
    const float* w_qkv = (const float*)d_in[1];
    const float* w_o   = (const float*)d_in[2];
    const float* w1    = (const float*)d_in[3];
    const float* b1    = (const float*)d_in[4];
    const float* w2    = (const float*)d_in[5];
    const float* b2    = (const float*)d_in[6];
    const float* ln1g  = (const float*)d_in[7];
    const float* ln1b  = (const float*)d_in[8];
    const float* ln2g  = (const float*)d_in[9];
    const float* ln2b  = (const float*)d_in[10];
    float* out = (float*)d_out;
    char* ws = (char*)d_ws;

    unsigned short* x1b = (unsigned short*)(ws);               // 32 MB  x1 bf16
    unsigned short* hb  = (unsigned short*)(ws + 33554432);    // 32 MB  h  bf16
    unsigned short* w1b = (unsigned short*)(ws + 67108864);    // 2 MB
    unsigned short* w2b = (unsigned short*)(ws + 69206016);    // 2 MB
    float* partial = (float*)(ws + 71303168);                  // 512 KB
    float* xsum    = (float*)(ws + 71827456);                  // 16 KB
    float* tvec    = (float*)(ws + 71843840);                  // 16 KB
    float* avec    = (float*)(ws + 71860224);                  // 16 KB

    cast_w_kernel<<<dim3(1024), 256, 0, stream>>>(w1, w2, w1b, w2b);
    colsum_partial_kernel<<<dim3(4, NB, 32), 256, 0, stream>>>(x, partial);
    colsum_reduce_kernel<<<dim3(4, NB), 256, 0, stream>>>(partial, xsum);
    matvec_kernel<<<dim3(64, NB), 256, 0, stream>>>(w_qkv + (size_t)2*DDIM*DDIM, xsum, tvec);
    matvec_kernel<<<dim3(64, NB), 256, 0, stream>>>(w_o, tvec, avec);
    ln1_kernel<<<dim3(MTOT), 256, 0, stream>>>(x, avec, ln1g, ln1b, x1b, out);
    gemm_kernel<1><<<dim3(128, 8), 256, 0, stream>>>((const bf16*)x1b, (const bf16*)w1b, b1, hb, nullptr, DDIM, DDIM);
    gemm_kernel<2><<<dim3(128, 8), 256, 0, stream>>>((const bf16*)hb, (const bf16*)w2b, b2, nullptr, out, DDIM, DDIM);
    ln2_kernel<<<dim3(MTOT), 256, 0, stream>>>(out, ln2g, ln2b);
}

// Round 2
// 191.313 us; speedup vs baseline: 1.2924x; 1.2924x over previous
//
#include <hip/hip_runtime.h>
#include <hip/hip_bf16.h>

typedef __hip_bfloat16 bf16;
typedef __attribute__((ext_vector_type(8))) short short8;
typedef __attribute__((ext_vector_type(4))) float f32x4;

#define DDIM 1024
#define SEQ  4096
#define NB   4
#define MTOT (NB*SEQ)   // 16384 rows

static __device__ __forceinline__ unsigned short f2bf(float f) {
    __hip_bfloat16 h = __float2bfloat16(f);
    unsigned short u; __builtin_memcpy(&u, &h, 2); return u;
}
static __device__ __forceinline__ float bf2f(unsigned short u) {
    __hip_bfloat16 h; __builtin_memcpy(&h, &u, 2); return __bfloat162float(h);
}

// ---------------------------------------------------------------- cast weights
__global__ __launch_bounds__(256) void cast_w_kernel(
    const float* __restrict__ w1, const float* __restrict__ w2,
    unsigned short* __restrict__ w1b, unsigned short* __restrict__ w2b)
{
    size_t idx = ((size_t)blockIdx.x*256 + threadIdx.x) * 4;   // grid 1024 -> 1M elems
    float4 a = *(const float4*)(w1 + idx);
    ushort4 o; o.x=f2bf(a.x); o.y=f2bf(a.y); o.z=f2bf(a.z); o.w=f2bf(a.w);
    *(ushort4*)(w1b + idx) = o;
    float4 b = *(const float4*)(w2 + idx);
    o.x=f2bf(b.x); o.y=f2bf(b.y); o.z=f2bf(b.z); o.w=f2bf(b.w);
    *(ushort4*)(w2b + idx) = o;
}

// ------------------------------------------------------- column sum of x (per batch)
__global__ __launch_bounds__(256) void colsum_partial_kernel(
    const float* __restrict__ x, float* __restrict__ partial)
{
    int d  = blockIdx.x*256 + threadIdx.x;
    int b  = blockIdx.y;
    int sl = blockIdx.z;
    const float* p = x + ((size_t)b*SEQ + (size_t)sl*128)*DDIM + d;
    float s = 0.f;
    #pragma unroll 4
    for (int i = 0; i < 128; ++i) s += p[(size_t)i*DDIM];
    partial[((size_t)sl*NB + b)*DDIM + d] = s;
}

__global__ __launch_bounds__(256) void colsum_reduce_kernel(
    const float* __restrict__ partial, float* __restrict__ xsum)
{
    int d = blockIdx.x*256 + threadIdx.x;
    int b = blockIdx.y;
    float s = 0.f;
    #pragma unroll
    for (int sl = 0; sl < 32; ++sl) s += partial[((size_t)sl*NB + b)*DDIM + d];
    xsum[b*DDIM + d] = s;
}

// ------------------------------------------------------- small matvec: vout = vin @ W^T
__global__ __launch_bounds__(256) void matvec_kernel(
    const float* __restrict__ W, const float* __restrict__ vin, float* __restrict__ vout)
{
    int b = blockIdx.y;
    int g = threadIdx.x >> 4;
    int t = threadIdx.x & 15;
    int e = blockIdx.x*16 + g;
    const float* w = W + (size_t)e*DDIM;
    const float* v = vin + b*DDIM;
    float s = 0.f;
    for (int k = t; k < DDIM; k += 16) s += w[k]*v[k];
    #pragma unroll
    for (int o = 8; o; o >>= 1) s += __shfl_down(s, o, 16);
    if (t == 0) vout[b*DDIM + e] = s;
}

// ------------------------------------------------------- LN1: x1 = LN(x + attnvec) -> bf16
__global__ __launch_bounds__(256) void ln1_kernel(
    const float* __restrict__ x, const float* __restrict__ avec,
    const float* __restrict__ g1, const float* __restrict__ b1,
    unsigned short* __restrict__ x1b)
{
    int row = blockIdx.x;
    int b   = row >> 12;          // row / SEQ
    int tid = threadIdx.x;
    const float4* xr = (const float4*)(x + (size_t)row*DDIM);
    const float4* av = (const float4*)(avec + (size_t)b*DDIM);
    float4 xv = xr[tid], a4 = av[tid];
    float y0 = xv.x+a4.x, y1 = xv.y+a4.y, y2 = xv.z+a4.z, y3 = xv.w+a4.w;
    float s  = y0+y1+y2+y3;
    float ss = y0*y0+y1*y1+y2*y2+y3*y3;
    #pragma unroll
    for (int o = 32; o; o >>= 1) { s += __shfl_down(s,o,64); ss += __shfl_down(ss,o,64); }
    __shared__ float red[8];
    if ((tid&63) == 0) { red[tid>>6] = s; red[4+(tid>>6)] = ss; }
    __syncthreads();
    float St = red[0]+red[1]+red[2]+red[3];
    float Sq = red[4]+red[5]+red[6]+red[7];
    float mu = St*(1.0f/DDIM);
    float rs = rsqrtf(Sq*(1.0f/DDIM) - mu*mu + 1e-5f);
    float4 g4 = ((const float4*)g1)[tid];
    float4 bb = ((const float4*)b1)[tid];
    ushort4 o;
    o.x = f2bf((y0-mu)*rs*g4.x + bb.x);
    o.y = f2bf((y1-mu)*rs*g4.y + bb.y);
    o.z = f2bf((y2-mu)*rs*g4.z + bb.z);
    o.w = f2bf((y3-mu)*rs*g4.w + bb.w);
    *(ushort4*)(x1b + (size_t)row*DDIM + tid*4) = o;
}

// ------------------------------------------------------- 256x256 2-phase dbuf MFMA GEMM
// C = A @ W^T ; MODE 1: outb = bf16(gelu(C+bias)) ; MODE 2: outf = C + bias + bf16resid
template<int MODE>
__global__ __launch_bounds__(512) void gemm256_kernel(
    const bf16* __restrict__ A, const bf16* __restrict__ Bw,
    const float* __restrict__ bias, const unsigned short* __restrict__ resid,
    unsigned short* __restrict__ outb, float* __restrict__ outf)
{
    constexpr int K = 1024, N = 1024, BK = 32;
    __shared__ __align__(16) bf16 lds[2][2][256*BK];   // 64 KB: [buf][A/B][256 rows x 32 k]
    const int tid  = threadIdx.x;
    const int wave = tid >> 6, lane = tid & 63;

    // T1: bijective XCD swizzle (grid 256, 8 XCDs, 32 blocks each), n-fastest decomposition
    int bid = blockIdx.x;
    int swz = (bid & 7) * 32 + (bid >> 3);
    const size_t bm = (size_t)(swz >> 2) * 256;
    const size_t bn = (size_t)(swz & 3) * 256;

    const int wm = wave >> 2;     // 0..1  (row half)
    const int wn = wave & 3;      // 0..3  (64-col strip)

    // staging geometry: thread covers linear LDS bytes p = i*8192 + tid*16, i in {0,1}
    // row = p/64 = i*128 + (tid>>2); in-row byte = (tid&3)*16, inverse-swizzled source
    const int sr = tid >> 2;
    const int sx = ((tid >> 3) & 3) << 4;            // ((row>>1)&3)<<4, i-independent
    const int sk = (((tid & 3) * 16) ^ sx) >> 1;     // source k element offset in row

    // fragment read geometry (ds_read_b128, swizzled)
    const int frow = lane & 15;
    const int fk2  = (lane >> 4) * 16;               // byte offset of lane's 8 bf16
    const int swo  = fk2 ^ (((frow >> 1) & 3) << 4); // T2 XOR swizzle on read
    const int rowA = wm*128 + frow;
    const int rowB = wn*64  + frow;

    f32x4 acc[8][4] = {};
    const bf16* Ab = A  + bm * K;
    const bf16* Bb = Bw + bn * K;

    auto stage = [&](int b, int kt) {
        int kel = kt * BK + sk;
        #pragma unroll
        for (int i = 0; i < 2; ++i) {
            int r = i*128 + sr;
            const bf16* ga = Ab + (size_t)r * K + kel;
            const bf16* gb = Bb + (size_t)r * K + kel;
            __builtin_amdgcn_global_load_lds(
                (const __attribute__((address_space(1))) void*)ga,
                (__attribute__((address_space(3))) void*)((char*)&lds[b][0][0] + i*8192 + wave*1024),
                16, 0, 0);
            __builtin_amdgcn_global_load_lds(
                (const __attribute__((address_space(1))) void*)gb,
                (__attribute__((address_space(3))) void*)((char*)&lds[b][1][0] + i*8192 + wave*1024),
                16, 0, 0);
        }
    };

    auto compute = [&](int b) {
        const char* LA = (const char*)&lds[b][0][0];
        const char* LB = (const char*)&lds[b][1][0];
        short8 af[8], bfr[4];
        #pragma unroll
        for (int m = 0; m < 8; ++m)
            af[m] = *(const short8*)(LA + (rowA + m*16)*64 + swo);
        #pragma unroll
        for (int n = 0; n < 4; ++n)
            bfr[n] = *(const short8*)(LB + (rowB + n*16)*64 + swo);
        __builtin_amdgcn_s_setprio(1);
        #pragma unroll
        for (int m = 0; m < 8; ++m)
            #pragma unroll
            for (int n = 0; n < 4; ++n)
                acc[m][n] = __builtin_amdgcn_mfma_f32_16x16x32_bf16(af[m], bfr[n], acc[m][n], 0, 0, 0);
        __builtin_amdgcn_s_setprio(0);
    };

    stage(0, 0);
    __syncthreads();
    int cur = 0;
    for (int t = 0; t < 31; ++t) {          // NT = K/BK = 32 tiles
        stage(cur ^ 1, t + 1);              // issue next-tile loads first (T3 recipe)
        compute(cur);
        __syncthreads();                    // vmcnt(0)+lgkmcnt(0)+barrier: next buf ready
        cur ^= 1;
    }
    compute(cur);

    // epilogue
    const int crow = (lane >> 4) * 4, ccol = lane & 15;
    #pragma unroll
    for (int n = 0; n < 4; ++n) {
        size_t col = bn + wn*64 + n*16 + ccol;
        float bv = bias[col];
        #pragma unroll
        for (int m = 0; m < 8; ++m) {
            #pragma unroll
            for (int r = 0; r < 4; ++r) {
                size_t row = bm + wm*128 + m*16 + crow + r;
                float v = acc[m][n][r] + bv;
                if (MODE == 1) {
                    float ge = 0.5f*v*(1.0f + erff(v*0.70710678118f));
                    outb[row*(size_t)N + col] = f2bf(ge);
                } else {
                    outf[row*(size_t)N + col] = v + bf2f(resid[row*(size_t)N + col]);
                }
            }
        }
    }
}

// ------------------------------------------------------- LN2 in-place on d_out
__global__ __launch_bounds__(256) void ln2_kernel(
    float* __restrict__ out, const float* __restrict__ g2, const float* __restrict__ b2)
{
    int row = blockIdx.x;
    int tid = threadIdx.x;
    float4* orow = (float4*)(out + (size_t)row*DDIM);
    float4 y = orow[tid];
    float s  = y.x+y.y+y.z+y.w;
    float ss = y.x*y.x+y.y*y.y+y.z*y.z+y.w*y.w;
    #pragma unroll
    for (int o = 32; o; o >>= 1) { s += __shfl_down(s,o,64); ss += __shfl_down(ss,o,64); }
    __shared__ float red[8];
    if ((tid&63) == 0) { red[tid>>6] = s; red[4+(tid>>6)] = ss; }
    __syncthreads();
    float St = red[0]+red[1]+red[2]+red[3];
    float Sq = red[4]+red[5]+red[6]+red[7];
    float mu = St*(1.0f/DDIM);
    float rs = rsqrtf(Sq*(1.0f/DDIM) - mu*mu + 1e-5f);
    float4 g4 = ((const float4*)g2)[tid];
    float4 bb = ((const float4*)b2)[tid];
    float4 n;
    n.x = (y.x-mu)*rs*g4.x + bb.x;
    n.y = (y.y-mu)*rs*g4.y + bb.y;
    n.z = (y.z-mu)*rs*g4.z + bb.z;
    n.w = (y.w-mu)*rs*g4.w + bb.w;
    orow[tid] = n;
}

// ---------------------------------------------------------------- launch
extern "C" void kernel_launch(void* const* d_in, const int* in_sizes, int n_in,
                              void* d_out, int out_size, void* d_ws, size_t ws_size,
                              hipStream_t stream)
{
    const float* x     = (const float*)d_in[0];
    const float* w_qkv = (const float*)d_in[1];
    const float* w_o   = (const float*)d_in[2];
    const float* w1    = (const float*)d_in[3];
    const float* b1    = (const float*)d_in[4];
    const float* w2    = (const float*)d_in[5];
    const float* b2    = (const float*)d_in[6];
    const float* ln1g  = (const float*)d_in[7];
    const float* ln1b  = (const float*)d_in[8];
    const float* ln2g  = (const float*)d_in[9];
    const float* ln2b  = (const float*)d_in[10];
    float* out = (float*)d_out;
    char* ws = (char*)d_ws;

    unsigned short* x1b = (unsigned short*)(ws);               // 32 MB  x1 bf16
    unsigned short* hb  = (unsigned short*)(ws + 33554432);    // 32 MB  h  bf16
    unsigned short* w1b = (unsigned short*)(ws + 67108864);    // 2 MB
    unsigned short* w2b = (unsigned short*)(ws + 69206016);    // 2 MB
    float* partial = (float*)(ws + 71303168);                  // 512 KB
    float* xsum    = (float*)(ws + 71827456);                  // 16 KB
    float* tvec    = (float*)(ws + 71843840);                  // 16 KB
    float* avec    = (float*)(ws + 71860224);                  // 16 KB

    cast_w_kernel<<<dim3(1024), 256, 0, stream>>>(w1, w2, w1b, w2b);
    colsum_partial_kernel<<<dim3(4, NB, 32), 256, 0, stream>>>(x, partial);
    colsum_reduce_kernel<<<dim3(4, NB), 256, 0, stream>>>(partial, xsum);
    matvec_kernel<<<dim3(64, NB), 256, 0, stream>>>(w_qkv + (size_t)2*DDIM*DDIM, xsum, tvec);
    matvec_kernel<<<dim3(64, NB), 256, 0, stream>>>(w_o, tvec, avec);
    ln1_kernel<<<dim3(MTOT), 256, 0, stream>>>(x, avec, ln1g, ln1b, x1b);
    gemm256_kernel<1><<<dim3(256), 512, 0, stream>>>(
        (const bf16*)x1b, (const bf16*)w1b, b1, nullptr, hb, nullptr);
    gemm256_kernel<2><<<dim3(256), 512, 0, stream>>>(
        (const bf16*)hb, (const bf16*)w2b, b2, x1b, nullptr, out);
    ln2_kernel<<<dim3(MTOT), 256, 0, stream>>>(out, ln2g, ln2b);
}

// Round 3
// 174.563 us; speedup vs baseline: 1.4164x; 1.0960x over previous
//
#include <hip/hip_runtime.h>
#include <hip/hip_bf16.h>

typedef __hip_bfloat16 bf16;
typedef __attribute__((ext_vector_type(8))) short short8;
typedef __attribute__((ext_vector_type(4))) float f32x4;

#define DDIM 1024
#define SEQ  4096
#define NB   4
#define MTOT (NB*SEQ)   // 16384 rows

static __device__ __forceinline__ unsigned short f2bf(float f) {
    __hip_bfloat16 h = __float2bfloat16(f);
    unsigned short u; __builtin_memcpy(&u, &h, 2); return u;
}
static __device__ __forceinline__ float bf2f(unsigned short u) {
    __hip_bfloat16 h; __builtin_memcpy(&h, &u, 2); return __bfloat162float(h);
}

// ---------------------------------------------------------------- cast weights
__global__ __launch_bounds__(256) void cast_w_kernel(
    const float* __restrict__ w1, const float* __restrict__ w2,
    unsigned short* __restrict__ w1b, unsigned short* __restrict__ w2b)
{
    size_t idx = ((size_t)blockIdx.x*256 + threadIdx.x) * 4;   // grid 1024 -> 1M elems
    float4 a = *(const float4*)(w1 + idx);
    ushort4 o; o.x=f2bf(a.x); o.y=f2bf(a.y); o.z=f2bf(a.z); o.w=f2bf(a.w);
    *(ushort4*)(w1b + idx) = o;
    float4 b = *(const float4*)(w2 + idx);
    o.x=f2bf(b.x); o.y=f2bf(b.y); o.z=f2bf(b.z); o.w=f2bf(b.w);
    *(ushort4*)(w2b + idx) = o;
}

// ------------------------------------------------------- column sum of x (per batch)
__global__ __launch_bounds__(256) void colsum_partial_kernel(
    const float* __restrict__ x, float* __restrict__ partial)
{
    int d  = blockIdx.x*256 + threadIdx.x;
    int b  = blockIdx.y;
    int sl = blockIdx.z;
    const float* p = x + ((size_t)b*SEQ + (size_t)sl*128)*DDIM + d;
    float s = 0.f;
    #pragma unroll 4
    for (int i = 0; i < 128; ++i) s += p[(size_t)i*DDIM];
    partial[((size_t)sl*NB + b)*DDIM + d] = s;
}

__global__ __launch_bounds__(256) void colsum_reduce_kernel(
    const float* __restrict__ partial, float* __restrict__ xsum)
{
    int d = blockIdx.x*256 + threadIdx.x;
    int b = blockIdx.y;
    float s = 0.f;
    #pragma unroll
    for (int sl = 0; sl < 32; ++sl) s += partial[((size_t)sl*NB + b)*DDIM + d];
    xsum[b*DDIM + d] = s;
}

// ------------------------------------------------------- small matvec: vout = vin @ W^T
__global__ __launch_bounds__(256) void matvec_kernel(
    const float* __restrict__ W, const float* __restrict__ vin, float* __restrict__ vout)
{
    int b = blockIdx.y;
    int g = threadIdx.x >> 4;
    int t = threadIdx.x & 15;
    int e = blockIdx.x*16 + g;
    const float* w = W + (size_t)e*DDIM;
    const float* v = vin + b*DDIM;
    float s = 0.f;
    for (int k = t; k < DDIM; k += 16) s += w[k]*v[k];
    #pragma unroll
    for (int o = 8; o; o >>= 1) s += __shfl_down(s, o, 16);
    if (t == 0) vout[b*DDIM + e] = s;
}

// ------------------------------------------------------- LN1: x1 = LN(x + attnvec) -> bf16
__global__ __launch_bounds__(256) void ln1_kernel(
    const float* __restrict__ x, const float* __restrict__ avec,
    const float* __restrict__ g1, const float* __restrict__ b1,
    unsigned short* __restrict__ x1b)
{
    int row = blockIdx.x;
    int b   = row >> 12;          // row / SEQ
    int tid = threadIdx.x;
    const float4* xr = (const float4*)(x + (size_t)row*DDIM);
    const float4* av = (const float4*)(avec + (size_t)b*DDIM);
    float4 xv = xr[tid], a4 = av[tid];
    float y0 = xv.x+a4.x, y1 = xv.y+a4.y, y2 = xv.z+a4.z, y3 = xv.w+a4.w;
    float s  = y0+y1+y2+y3;
    float ss = y0*y0+y1*y1+y2*y2+y3*y3;
    #pragma unroll
    for (int o = 32; o; o >>= 1) { s += __shfl_down(s,o,64); ss += __shfl_down(ss,o,64); }
    __shared__ float red[8];
    if ((tid&63) == 0) { red[tid>>6] = s; red[4+(tid>>6)] = ss; }
    __syncthreads();
    float St = red[0]+red[1]+red[2]+red[3];
    float Sq = red[4]+red[5]+red[6]+red[7];
    float mu = St*(1.0f/DDIM);
    float rs = rsqrtf(Sq*(1.0f/DDIM) - mu*mu + 1e-5f);
    float4 g4 = ((const float4*)g1)[tid];
    float4 bb = ((const float4*)b1)[tid];
    ushort4 o;
    o.x = f2bf((y0-mu)*rs*g4.x + bb.x);
    o.y = f2bf((y1-mu)*rs*g4.y + bb.y);
    o.z = f2bf((y2-mu)*rs*g4.z + bb.z);
    o.w = f2bf((y3-mu)*rs*g4.w + bb.w);
    *(ushort4*)(x1b + (size_t)row*DDIM + tid*4) = o;
}

// ------------------------------------------------------- 128x128 BK=64 counted-vmcnt GEMM
// C = A @ W^T ; MODE 1: outb = bf16(gelu(C+bias)) ; MODE 2: outf = C + bias + bf16resid
// 2 blocks/CU (64 KB LDS), double-buffered, s_waitcnt vmcnt(8) (never 0 in loop).
template<int MODE>
__global__ __launch_bounds__(256, 2) void gemm128_kernel(
    const bf16* __restrict__ A, const bf16* __restrict__ Bw,
    const float* __restrict__ bias, const unsigned short* __restrict__ resid,
    unsigned short* __restrict__ outb, float* __restrict__ outf)
{
    constexpr int K = 1024, N = 1024, BK = 64, NT = K / BK;   // 16 K-tiles
    __shared__ __align__(16) bf16 lds[2][2][128*BK];          // 64 KB: [buf][A/B][128r x 64k]
    const int tid  = threadIdx.x;
    const int wave = tid >> 6, lane = tid & 63;

    // T1: bijective XCD swizzle. grid 1024, 8 XCDs: each XCD gets 16 M x 8 N contiguous panel.
    int bid = blockIdx.x;
    int swz = (bid & 7) * 128 + (bid >> 3);
    const size_t bm = (size_t)(swz >> 3) * 128;   // 0..127
    const size_t bn = (size_t)(swz & 7) * 128;    // 0..7

    const int wm = wave >> 1;     // 0..1
    const int wn = wave & 1;      // 0..1

    // ---- staging geometry (rule #21: linear LDS dest, inverse-swizzled global source)
    // gload g covers LDS bytes [g*4096 + tid*16): row = g*32 + (tid>>3), physslot = tid&7.
    // physical slot s at row r holds logical k-block (s ^ (r&7)); r&7 == (tid>>3)&7.
    const int srow = tid >> 3;                                  // + g*32
    const int skel = (((tid & 7) ^ ((tid >> 3) & 7)) << 3);     // k element offset, g-invariant

    // ---- fragment read geometry (ds_read_b128, swizzled): logical k-block b = ks*4 + (lane>>4)
    const int frow = lane & 15;
    int foff[2];
    #pragma unroll
    for (int ks = 0; ks < 2; ++ks)
        foff[ks] = frow*128 + (((ks*4 + (lane >> 4)) ^ (lane & 7)) << 4);

    f32x4 acc[4][4] = {};
    const bf16* Ab = A  + bm * K;
    const bf16* Bb = Bw + bn * K;

    auto stage = [&](int b, int kt) {        // 8 global_load_lds (16B each)
        #pragma unroll
        for (int mat = 0; mat < 2; ++mat) {
            const bf16* src = (mat == 0 ? Ab : Bb);
            #pragma unroll
            for (int g = 0; g < 4; ++g) {
                int row = g*32 + srow;
                const bf16* gp = src + (size_t)row * K + kt*BK + skel;
                __builtin_amdgcn_global_load_lds(
                    (const __attribute__((address_space(1))) void*)gp,
                    (__attribute__((address_space(3))) void*)
                        ((char*)&lds[b][mat][0] + g*4096 + wave*1024),
                    16, 0, 0);
            }
        }
    };

    stage(0, 0);                                  // prologue: tile 0 in flight (8 loads)

    #pragma unroll 2
    for (int t = 0; t < NT; ++t) {
        const int cur = t & 1;
        if (t < NT-1) {
            stage(cur ^ 1, t + 1);                // issue next tile first (8 loads)
            asm volatile("s_waitcnt vmcnt(8)" ::: "memory");   // tile t landed (per-wave)
        } else {
            asm volatile("s_waitcnt vmcnt(0)" ::: "memory");   // tail only
        }
        __builtin_amdgcn_s_barrier();             // collective: ALL waves' loads landed

        const char* LA = (const char*)&lds[cur][0][0] + wm*8192;
        const char* LB = (const char*)&lds[cur][1][0] + wn*8192;
        #pragma unroll
        for (int ks = 0; ks < 2; ++ks) {
            short8 af[4], bfr[4];
            #pragma unroll
            for (int m = 0; m < 4; ++m) af[m]  = *(const short8*)(LA + m*2048 + foff[ks]);
            #pragma unroll
            for (int n = 0; n < 4; ++n) bfr[n] = *(const short8*)(LB + n*2048 + foff[ks]);
            __builtin_amdgcn_s_setprio(1);
            #pragma unroll
            for (int m = 0; m < 4; ++m)
                #pragma unroll
                for (int n = 0; n < 4; ++n)
                    acc[m][n] = __builtin_amdgcn_mfma_f32_16x16x32_bf16(af[m], bfr[n], acc[m][n], 0, 0, 0);
            __builtin_amdgcn_s_setprio(0);
        }
        __builtin_amdgcn_s_barrier();             // buf `cur` free: next iter may overwrite
    }

    // epilogue
    const int crow = (lane >> 4) * 4, ccol = lane & 15;
    #pragma unroll
    for (int n = 0; n < 4; ++n) {
        size_t col = bn + wn*64 + n*16 + ccol;
        float bv = bias[col];
        #pragma unroll
        for (int m = 0; m < 4; ++m) {
            #pragma unroll
            for (int r = 0; r < 4; ++r) {
                size_t row = bm + wm*64 + m*16 + crow + r;
                float v = acc[m][n][r] + bv;
                if (MODE == 1) {
                    float ge = 0.5f*v*(1.0f + erff(v*0.70710678118f));
                    outb[row*(size_t)N + col] = f2bf(ge);
                } else {
                    outf[row*(size_t)N + col] = v + bf2f(resid[row*(size_t)N + col]);
                }
            }
        }
    }
}

// ------------------------------------------------------- LN2 in-place on d_out
__global__ __launch_bounds__(256) void ln2_kernel(
    float* __restrict__ out, const float* __restrict__ g2, const float* __restrict__ b2)
{
    int row = blockIdx.x;
    int tid = threadIdx.x;
    float4* orow = (float4*)(out + (size_t)row*DDIM);
    float4 y = orow[tid];
    float s  = y.x+y.y+y.z+y.w;
    float ss = y.x*y.x+y.y*y.y+y.z*y.z+y.w*y.w;
    #pragma unroll
    for (int o = 32; o; o >>= 1) { s += __shfl_down(s,o,64); ss += __shfl_down(ss,o,64); }
    __shared__ float red[8];
    if ((tid&63) == 0) { red[tid>>6] = s; red[4+(tid>>6)] = ss; }
    __syncthreads();
    float St = red[0]+red[1]+red[2]+red[3];
    float Sq = red[4]+red[5]+red[6]+red[7];
    float mu = St*(1.0f/DDIM);
    float rs = rsqrtf(Sq*(1.0f/DDIM) - mu*mu + 1e-5f);
    float4 g4 = ((const float4*)g2)[tid];
    float4 bb = ((const float4*)b2)[tid];
    float4 n;
    n.x = (y.x-mu)*rs*g4.x + bb.x;
    n.y = (y.y-mu)*rs*g4.y + bb.y;
    n.z = (y.z-mu)*rs*g4.z + bb.z;
    n.w = (y.w-mu)*rs*g4.w + bb.w;
    orow[tid] = n;
}

// ---------------------------------------------------------------- launch
extern "C" void kernel_launch(void* const* d_in, const int* in_sizes, int n_in,
                              void* d_out, int out_size, void* d_ws, size_t ws_size,
                              hipStream_t stream)
{
    const float* x     = (const float*)d_in[0];
    const float* w_qkv = (const float*)d_in[1];
    const float* w_o   = (const float*)d_in[2];
    const float* w1    = (const float*)d_in[3];
    const float* b1    = (const float*)d_in[4];
    const float* w2    = (const float*)d_in[5];
    const float* b2    = (const float*)d_in[6];
    const float* ln1g  = (const float*)d_in[7];
    const float* ln1b  = (const float*)d_in[8];
    const float* ln2g  = (const float*)d_in[9];
    const float* ln2b  = (const float*)d_in[10];
    float* out = (float*)d_out;
    char* ws = (char*)d_ws;

    unsigned short* x1b = (unsigned short*)(ws);               // 32 MB  x1 bf16
    unsigned short* hb  = (unsigned short*)(ws + 33554432);    // 32 MB  h  bf16
    unsigned short* w1b = (unsigned short*)(ws + 67108864);    // 2 MB
    unsigned short* w2b = (unsigned short*)(ws + 69206016);    // 2 MB
    float* partial = (float*)(ws + 71303168);                  // 512 KB
    float* xsum    = (float*)(ws + 71827456);                  // 16 KB
    float* tvec    = (float*)(ws + 71843840);                  // 16 KB
    float* avec    = (float*)(ws + 71860224);                  // 16 KB

    cast_w_kernel<<<dim3(1024), 256, 0, stream>>>(w1, w2, w1b, w2b);
    colsum_partial_kernel<<<dim3(4, NB, 32), 256, 0, stream>>>(x, partial);
    colsum_reduce_kernel<<<dim3(4, NB), 256, 0, stream>>>(partial, xsum);
    matvec_kernel<<<dim3(64, NB), 256, 0, stream>>>(w_qkv + (size_t)2*DDIM*DDIM, xsum, tvec);
    matvec_kernel<<<dim3(64, NB), 256, 0, stream>>>(w_o, tvec, avec);
    ln1_kernel<<<dim3(MTOT), 256, 0, stream>>>(x, avec, ln1g, ln1b, x1b);
    gemm128_kernel<1><<<dim3(1024), 256, 0, stream>>>(
        (const bf16*)x1b, (const bf16*)w1b, b1, nullptr, hb, nullptr);
    gemm128_kernel<2><<<dim3(1024), 256, 0, stream>>>(
        (const bf16*)hb, (const bf16*)w2b, b2, x1b, nullptr, out);
    ln2_kernel<<<dim3(MTOT), 256, 0, stream>>>(out, ln2g, ln2b);
}